// Round 4
// baseline (299.001 us; speedup 1.0000x reference)
//
#include <hip/hip_runtime.h>
#include <hip/hip_bf16.h>

// ChildSumTreeLSTM, complete binary tree heap layout (children of n: 2n+1, 2n+2).
// R14: cross-round ledger shows e2e - K_A = 185 us invariant (R10-R13) => the
// tail (K_B..K_E + 5 graph-node boundaries) dominates, not K_A. This round:
//  (1) K_B+K_C+K_D+K_E merged into ONE persistent tail_kernel (grid 256 = 1
//      block/CU, co-resident by construction) using device-scope software
//      barriers (atomicAdd + __threadfence release/acquire; counters zeroed by
//      prep each replay -> graph-capture safe). Removes 3 launch+drain
//      boundaries; B fragments loaded once for all 4 phases; tail becomes one
//      profiled dispatch so its counters surface next round.
//      Phases: B = 512 tiles d14+d13 (2/block) | gbar | C = 128 tiles d12+d11
//      (blocks<128) | gbar | D = 32 subtrees d10..d5 (blocks<32, k23-in-LDS) |
//      gbar | E = block 0: d4..d0 + projection.
//  (2) ftanh = 1 - 2/(e^{2v}+1): clamp-free (inf-safe algebraically), -2 VALU.
// K_A unchanged: kd2r 2-barrier pipelined kernel (R13, 56 us).
// History: R11 2-blocks/CU impossible (b[32]=128 AGPR + 124 VGPR = 252 regs ->
// hard 2 waves/SIMD); R12 global-streamed B inside MFMA loop serializes.
// Bsw = fragment-stream-ordered [W/2 | U] (f-gate W unhalved), gates [i,o,u,f];
// child row r computes [x_par; h_child]@B^T, epilogue sums row pairs in-lane.

#define DEPTH 17
#define NTREE ((1 << DEPTH) - 1)  // 131071
#define DIM 128
#define XSTR 136  // bf16 LDS row stride (shorts) = 272 B (16B-aligned, 2-way banks = free)
#define HSTR 136
#define CSTR 132  // fp32 LDS row stride (floats)

typedef __attribute__((ext_vector_type(8))) short short8;
typedef __attribute__((ext_vector_type(4))) float float4v;

__device__ __forceinline__ float sigm(float v) {
    return __fdividef(1.0f, 1.0f + __expf(-v));
}
__device__ __forceinline__ float ftanh(float v) {
    float e = __expf(2.0f * v);                  // inf-safe: e=inf -> 1, e=0 -> -1
    return 1.0f - __fdividef(2.0f, e + 1.0f);
}

__device__ __forceinline__ unsigned short f2bf(float f) {
    __bf16 h = (__bf16)f;  // HW RNE cvt
    unsigned short r;
    __builtin_memcpy(&r, &h, 2);
    return r;
}
__device__ __forceinline__ float bf2f(unsigned short s) {
    union { unsigned u; float f; } a; a.u = ((unsigned)s) << 16;
    return a.f;
}

struct WPtrs {
    const float* W[4];  const float* U[4];
    const float* bW[4]; const float* bU[4];
};

// Bsw[w][ks][g][lane][j] (w:8, ks:8, g:4, lane:64, j:8) = fragment-stream order.
__global__ __launch_bounds__(256) void prep_kernel(WPtrs p, unsigned short* __restrict__ Bsw,
                                                   float* __restrict__ biasWU, float* __restrict__ biasL,
                                                   unsigned* __restrict__ bar) {
    int idx = blockIdx.x * 256 + threadIdx.x;  // 0 .. 131071
    int j = idx & 7;
    int lane = (idx >> 3) & 63;
    int g = (idx >> 9) & 3;
    int ks = (idx >> 11) & 7;
    int w = idx >> 14;
    int L = lane & 15, q = lane >> 4;
    int c = w * 16 + L;
    int k = ks * 32 + q * 8 + j;
    float v = (k < 128) ? p.W[g][c * 128 + k] * (g == 3 ? 1.0f : 0.5f)
                        : p.U[g][c * 128 + (k - 128)];
    Bsw[idx] = f2bf(v);
    if (idx < 512) {
        int gg = idx >> 7, cc = idx & 127;
        biasWU[idx] = p.bW[gg][cc] + p.bU[gg][cc];
        biasL[idx]  = p.bW[gg][cc];
    }
    if (idx < 4) bar[idx] = 0u;  // reset software-barrier counters each replay
}

// ---------- K_A: persistent depth-2 leaf kernel, 2 barriers/tile (R13) ----------
template <bool LEAF0>
__global__ __launch_bounds__(512, 2) void kd2r_kernel(
    const float* __restrict__ x, const unsigned short* __restrict__ Bsw,
    const float* __restrict__ biasL, const float* __restrict__ biasWU,
    unsigned short* __restrict__ hbf, float* __restrict__ cbuf,
    int x0base, int x1base, int ntiles) {
    __shared__ __align__(16) unsigned short xs[2][48 * XSTR];
    __shared__ __align__(16) unsigned short hc[LEAF0 ? 16 : 64 * XSTR];
    __shared__ __align__(16) unsigned short h0[32 * XSTR];
    __shared__ __align__(16) unsigned short c0[32 * XSTR];
    __shared__ __align__(16) unsigned short hA1[16 * XSTR];
    __shared__ __align__(16) float cA1[16 * CSTR];

    const int tid = threadIdx.x;
    const int w = tid >> 6, lane = tid & 63, L = lane & 15, q = lane >> 4;
    const int ch = w * 16 + L;

    short8 b[32];
#pragma unroll
    for (int t = 0; t < 32; ++t)
        b[t] = *(const short8*)(Bsw + ((size_t)w << 14) + (t << 9) + lane * 8);

    float4 pfx[3];
    {
        const long tt = blockIdx.x;
        const long n0 = (long)x0base + tt * 32, n1 = (long)x1base + tt * 16;
#pragma unroll
        for (int k = 0; k < 3; ++k) {
            const int i = tid + 512 * k;
            const int row = i >> 5, j = i & 31;
            const long node = (row < 32) ? (n0 + row) : (n1 + (row - 32));
            pfx[k] = *(const float4*)(x + (size_t)node * DIM + j * 4);
        }
    }

    for (int it = 0; it < ntiles; ++it) {
        const long tt = (long)it * gridDim.x + blockIdx.x;
        const long n0 = (long)x0base + tt * 32;
        const long n1 = (long)x1base + tt * 16;
        const long cb = 2 * n0 + 1;
        const int pc = it & 1;
        unsigned short* xsp = xs[pc];

#pragma unroll
        for (int k = 0; k < 3; ++k) {
            const int i = tid + 512 * k;
            const int row = i >> 5, j = i & 31;
            ushort4 o;
            o.x = f2bf(pfx[k].x); o.y = f2bf(pfx[k].y);
            o.z = f2bf(pfx[k].z); o.w = f2bf(pfx[k].w);
            *(ushort4*)(xsp + row * XSTR + j * 4) = o;
        }
        if (!LEAF0) {
            for (int i = tid; i < 64 * 16; i += 512) {
                const int row = i >> 4, g = i & 15;
                *(uint4*)(hc + row * XSTR + g * 8) =
                    *(const uint4*)(hbf + (size_t)(cb + row) * DIM + g * 8);
            }
        }
        __syncthreads();  // B1

        if (it + 1 < ntiles) {
            const long tn = tt + gridDim.x;
            const long m0 = (long)x0base + tn * 32, m1 = (long)x1base + tn * 16;
#pragma unroll
            for (int k = 0; k < 3; ++k) {
                const int i = tid + 512 * k;
                const int row = i >> 5, j = i & 31;
                const long node = (row < 32) ? (m0 + row) : (m1 + (row - 32));
                pfx[k] = *(const float4*)(x + (size_t)node * DIM + j * 4);
            }
        }

        if (it > 0) {  // store tile t-1's level-1 rows (overlaps L0)
            const long pn1 = n1 - (long)gridDim.x * 16;
            for (int i = tid; i < 16 * 16; i += 512) {
                const int row = i >> 4, g = i & 15;
                *(uint4*)(hbf + (size_t)(pn1 + row) * DIM + g * 8) = *(const uint4*)(hA1 + row * XSTR + g * 8);
            }
            for (int i = tid; i < 16 * 32; i += 512) {
                const int row = i >> 5, j = i & 31;
                *(float4*)(cbuf + (size_t)(pn1 + row) * DIM + j * 4) = *(const float4*)(cA1 + row * CSTR + j * 4);
            }
        }

        // ---- level 0 ----
        if (LEAF0) {
            float4v acc[2][3];
#pragma unroll
            for (int mm = 0; mm < 2; ++mm)
#pragma unroll
                for (int g = 0; g < 3; ++g) acc[mm][g] = (float4v){0.f, 0.f, 0.f, 0.f};
#pragma unroll
            for (int ks = 0; ks < 4; ++ks) {
                short8 a[2];
                a[0] = *(const short8*)(xsp + L * XSTR + ks * 32 + q * 8);
                a[1] = *(const short8*)(xsp + (16 + L) * XSTR + ks * 32 + q * 8);
#pragma unroll
                for (int g = 0; g < 3; ++g)
#pragma unroll
                    for (int mm = 0; mm < 2; ++mm)
                        acc[mm][g] = __builtin_amdgcn_mfma_f32_16x16x32_bf16(a[mm], b[ks * 4 + g], acc[mm][g], 0, 0, 0);
            }
#pragma unroll
            for (int mm = 0; mm < 2; ++mm)
#pragma unroll
                for (int r = 0; r < 4; ++r) {
                    const int nl = 16 * mm + q * 4 + r;
                    float iv = sigm(2.f * acc[mm][0][r] + biasL[ch]);
                    float ov = sigm(2.f * acc[mm][1][r] + biasL[128 + ch]);
                    float uv = ftanh(2.f * acc[mm][2][r] + biasL[256 + ch]);
                    float cv = iv * uv;
                    c0[nl * XSTR + ch] = f2bf(cv);
                    h0[nl * XSTR + ch] = f2bf(ov * ftanh(cv));
                }
        } else {
            for (int mc = 0; mc < 4; mc += 2) {
                float4v acc[2][4];
#pragma unroll
                for (int mm = 0; mm < 2; ++mm)
#pragma unroll
                    for (int g = 0; g < 4; ++g) acc[mm][g] = (float4v){0.f, 0.f, 0.f, 0.f};
#pragma unroll
                for (int ks = 0; ks < 8; ++ks) {
                    const int kk = ks * 32;
                    short8 a[2];
#pragma unroll
                    for (int mm = 0; mm < 2; ++mm) {
                        if (kk < 128)
                            a[mm] = *(const short8*)(xsp + (8 * (mc + mm) + (L >> 1)) * XSTR + kk + q * 8);
                        else
                            a[mm] = *(const short8*)(hc + (16 * (mc + mm) + L) * XSTR + (kk - 128) + q * 8);
                    }
#pragma unroll
                    for (int g = 0; g < 4; ++g)
#pragma unroll
                        for (int mm = 0; mm < 2; ++mm)
                            acc[mm][g] = __builtin_amdgcn_mfma_f32_16x16x32_bf16(a[mm], b[ks * 4 + g], acc[mm][g], 0, 0, 0);
                }
#pragma unroll
                for (int mm = 0; mm < 2; ++mm)
#pragma unroll
                    for (int e = 0; e < 2; ++e) {
                        const int nl = 8 * (mc + mm) + 2 * q + e;
                        const int r0 = 2 * e, r1 = 2 * e + 1;
                        float iv = sigm(acc[mm][0][r0] + acc[mm][0][r1] + biasWU[ch]);
                        float ov = sigm(acc[mm][1][r0] + acc[mm][1][r1] + biasWU[128 + ch]);
                        float uv = ftanh(acc[mm][2][r0] + acc[mm][2][r1] + biasWU[256 + ch]);
                        float fl = sigm(acc[mm][3][r0] + biasWU[384 + ch]);
                        float fr = sigm(acc[mm][3][r1] + biasWU[384 + ch]);
                        float cl = cbuf[(size_t)(cb + 2 * nl) * DIM + ch];
                        float cr = cbuf[(size_t)(cb + 2 * nl + 1) * DIM + ch];
                        float cv = iv * uv + fl * cl + fr * cr;
                        c0[nl * XSTR + ch] = f2bf(cv);
                        h0[nl * XSTR + ch] = f2bf(ov * ftanh(cv));
                    }
            }
        }
        __syncthreads();  // B2

        // ---- level 1 ----
        {
            float4v acc[2][4];
#pragma unroll
            for (int mm = 0; mm < 2; ++mm)
#pragma unroll
                for (int g = 0; g < 4; ++g) acc[mm][g] = (float4v){0.f, 0.f, 0.f, 0.f};
#pragma unroll
            for (int ks = 0; ks < 8; ++ks) {
                const int kk = ks * 32;
                short8 a[2];
#pragma unroll
                for (int mm = 0; mm < 2; ++mm) {
                    if (kk < 128)
                        a[mm] = *(const short8*)(xsp + (32 + 8 * mm + (L >> 1)) * XSTR + kk + q * 8);
                    else
                        a[mm] = *(const short8*)(h0 + (16 * mm + L) * XSTR + (kk - 128) + q * 8);
                }
#pragma unroll
                for (int g = 0; g < 4; ++g)
#pragma unroll
                    for (int mm = 0; mm < 2; ++mm)
                        acc[mm][g] = __builtin_amdgcn_mfma_f32_16x16x32_bf16(a[mm], b[ks * 4 + g], acc[mm][g], 0, 0, 0);
            }
#pragma unroll
            for (int mm = 0; mm < 2; ++mm)
#pragma unroll
                for (int e = 0; e < 2; ++e) {
                    const int nl = 8 * mm + 2 * q + e;
                    const int r0 = 2 * e, r1 = 2 * e + 1;
                    float iv = sigm(acc[mm][0][r0] + acc[mm][0][r1] + biasWU[ch]);
                    float ov = sigm(acc[mm][1][r0] + acc[mm][1][r1] + biasWU[128 + ch]);
                    float uv = ftanh(acc[mm][2][r0] + acc[mm][2][r1] + biasWU[256 + ch]);
                    float fl = sigm(acc[mm][3][r0] + biasWU[384 + ch]);
                    float fr = sigm(acc[mm][3][r1] + biasWU[384 + ch]);
                    float cl = bf2f(c0[(2 * nl) * XSTR + ch]);
                    float cr = bf2f(c0[(2 * nl + 1) * XSTR + ch]);
                    float cv = iv * uv + fl * cl + fr * cr;
                    cA1[nl * CSTR + ch] = cv;
                    hA1[nl * XSTR + ch] = f2bf(ov * ftanh(cv));
                }
        }
    }

    __syncthreads();
    {
        const long tl = (long)(ntiles - 1) * gridDim.x + blockIdx.x;
        const long n1 = (long)x1base + tl * 16;
        for (int i = tid; i < 16 * 16; i += 512) {
            const int row = i >> 4, g = i & 15;
            *(uint4*)(hbf + (size_t)(n1 + row) * DIM + g * 8) = *(const uint4*)(hA1 + row * XSTR + g * 8);
        }
        for (int i = tid; i < 16 * 32; i += 512) {
            const int row = i >> 5, j = i & 31;
            *(float4*)(cbuf + (size_t)(n1 + row) * DIM + j * 4) = *(const float4*)(cA1 + row * CSTR + j * 4);
        }
    }
}

// ---------- device-scope software grid barrier ----------
// Safe: grid=256 blocks at 1 block/CU (LDS 60.7KB) on 256 CUs => all co-resident.
// Release: __threadfence before arrive; Acquire: __threadfence after observing.
__device__ __forceinline__ void gbar(unsigned* cnt, unsigned target) {
    __syncthreads();
    if (threadIdx.x == 0) {
        __threadfence();
        atomicAdd(cnt, 1u);
        while (__hip_atomic_load(cnt, __ATOMIC_RELAXED, __HIP_MEMORY_SCOPE_AGENT) < target)
            __builtin_amdgcn_s_sleep(2);
        __threadfence();
    }
    __syncthreads();
}

// ---------- one non-leaf depth-2 tile (simple 3-barrier body) ----------
__device__ void kd2_tile(const float* __restrict__ x, const short8 (&b)[32],
                         const float* __restrict__ biasWU,
                         unsigned short* __restrict__ hbf, float* __restrict__ cbuf,
                         long n0, long n1,
                         unsigned short* xs, unsigned short* hc, unsigned short* h0,
                         unsigned short* c0, unsigned short* hA1, float* cA1,
                         int tid, int L, int q, int ch) {
    const long cb = 2 * n0 + 1;
    for (int i = tid; i < 48 * 32; i += 512) {
        const int row = i >> 5, j = i & 31;
        const long node = (row < 32) ? (n0 + row) : (n1 + (row - 32));
        float4 v = *(const float4*)(x + (size_t)node * DIM + j * 4);
        ushort4 o;
        o.x = f2bf(v.x); o.y = f2bf(v.y); o.z = f2bf(v.z); o.w = f2bf(v.w);
        *(ushort4*)(xs + row * XSTR + j * 4) = o;
    }
    for (int i = tid; i < 64 * 16; i += 512) {
        const int row = i >> 4, g = i & 15;
        *(uint4*)(hc + row * XSTR + g * 8) = *(const uint4*)(hbf + (size_t)(cb + row) * DIM + g * 8);
    }
    __syncthreads();

    // ---- level 0: 32 nodes (children from global hbf/cbuf) ----
    for (int mc = 0; mc < 4; mc += 2) {
        float4v acc[2][4];
#pragma unroll
        for (int mm = 0; mm < 2; ++mm)
#pragma unroll
            for (int g = 0; g < 4; ++g) acc[mm][g] = (float4v){0.f, 0.f, 0.f, 0.f};
#pragma unroll
        for (int ks = 0; ks < 8; ++ks) {
            const int kk = ks * 32;
            short8 a[2];
#pragma unroll
            for (int mm = 0; mm < 2; ++mm) {
                if (kk < 128)
                    a[mm] = *(const short8*)(xs + (8 * (mc + mm) + (L >> 1)) * XSTR + kk + q * 8);
                else
                    a[mm] = *(const short8*)(hc + (16 * (mc + mm) + L) * XSTR + (kk - 128) + q * 8);
            }
#pragma unroll
            for (int g = 0; g < 4; ++g)
#pragma unroll
                for (int mm = 0; mm < 2; ++mm)
                    acc[mm][g] = __builtin_amdgcn_mfma_f32_16x16x32_bf16(a[mm], b[ks * 4 + g], acc[mm][g], 0, 0, 0);
        }
#pragma unroll
        for (int mm = 0; mm < 2; ++mm)
#pragma unroll
            for (int e = 0; e < 2; ++e) {
                const int nl = 8 * (mc + mm) + 2 * q + e;
                const int r0 = 2 * e, r1 = 2 * e + 1;
                float iv = sigm(acc[mm][0][r0] + acc[mm][0][r1] + biasWU[ch]);
                float ov = sigm(acc[mm][1][r0] + acc[mm][1][r1] + biasWU[128 + ch]);
                float uv = ftanh(acc[mm][2][r0] + acc[mm][2][r1] + biasWU[256 + ch]);
                float fl = sigm(acc[mm][3][r0] + biasWU[384 + ch]);
                float fr = sigm(acc[mm][3][r1] + biasWU[384 + ch]);
                float cl = cbuf[(size_t)(cb + 2 * nl) * DIM + ch];
                float cr = cbuf[(size_t)(cb + 2 * nl + 1) * DIM + ch];
                float cv = iv * uv + fl * cl + fr * cr;
                c0[nl * XSTR + ch] = f2bf(cv);
                h0[nl * XSTR + ch] = f2bf(ov * ftanh(cv));
            }
    }
    __syncthreads();

    // ---- level 1: 16 parents (children in LDS) ----
    {
        float4v acc[2][4];
#pragma unroll
        for (int mm = 0; mm < 2; ++mm)
#pragma unroll
            for (int g = 0; g < 4; ++g) acc[mm][g] = (float4v){0.f, 0.f, 0.f, 0.f};
#pragma unroll
        for (int ks = 0; ks < 8; ++ks) {
            const int kk = ks * 32;
            short8 a[2];
#pragma unroll
            for (int mm = 0; mm < 2; ++mm) {
                if (kk < 128)
                    a[mm] = *(const short8*)(xs + (32 + 8 * mm + (L >> 1)) * XSTR + kk + q * 8);
                else
                    a[mm] = *(const short8*)(h0 + (16 * mm + L) * XSTR + (kk - 128) + q * 8);
            }
#pragma unroll
            for (int g = 0; g < 4; ++g)
#pragma unroll
                for (int mm = 0; mm < 2; ++mm)
                    acc[mm][g] = __builtin_amdgcn_mfma_f32_16x16x32_bf16(a[mm], b[ks * 4 + g], acc[mm][g], 0, 0, 0);
        }
#pragma unroll
        for (int mm = 0; mm < 2; ++mm)
#pragma unroll
            for (int e = 0; e < 2; ++e) {
                const int nl = 8 * mm + 2 * q + e;
                const int r0 = 2 * e, r1 = 2 * e + 1;
                float iv = sigm(acc[mm][0][r0] + acc[mm][0][r1] + biasWU[ch]);
                float ov = sigm(acc[mm][1][r0] + acc[mm][1][r1] + biasWU[128 + ch]);
                float uv = ftanh(acc[mm][2][r0] + acc[mm][2][r1] + biasWU[256 + ch]);
                float fl = sigm(acc[mm][3][r0] + biasWU[384 + ch]);
                float fr = sigm(acc[mm][3][r1] + biasWU[384 + ch]);
                float cl = bf2f(c0[(2 * nl) * XSTR + ch]);
                float cr = bf2f(c0[(2 * nl + 1) * XSTR + ch]);
                float cv = iv * uv + fl * cl + fr * cr;
                cA1[nl * CSTR + ch] = cv;
                hA1[nl * XSTR + ch] = f2bf(ov * ftanh(cv));
            }
    }
    __syncthreads();

    for (int i = tid; i < 16 * 16; i += 512) {
        const int row = i >> 4, g = i & 15;
        *(uint4*)(hbf + (size_t)(n1 + row) * DIM + g * 8) = *(const uint4*)(hA1 + row * XSTR + g * 8);
    }
    for (int i = tid; i < 16 * 32; i += 512) {
        const int row = i >> 5, j = i & 31;
        *(float4*)(cbuf + (size_t)(n1 + row) * DIM + j * 4) = *(const float4*)(cA1 + row * CSTR + j * 4);
    }
}

// ---------- k23: fused multi-level subtree level (unchanged) ----------
template <bool GCH>
__device__ __forceinline__ void internal_level(
    const unsigned short* xc,
    const unsigned short* hin_l, const float* cin_l,
    const unsigned short* __restrict__ hin_g, const float* __restrict__ cin_g, long cb,
    unsigned short* ho, int ho_str, float* co, int co_str, int cnt,
    const short8 (&b)[32], const float* __restrict__ biasWU,
    int L, int q, int ch) {
    const int rows = 2 * cnt;
    const int mt = (rows + 15) >> 4;
    for (int mc = 0; mc < mt; mc += 2) {
        const int mm_n = (mt - mc >= 2) ? 2 : 1;
        float4v acc[2][4];
#pragma unroll
        for (int mm = 0; mm < 2; ++mm)
#pragma unroll
            for (int g = 0; g < 4; ++g) acc[mm][g] = (float4v){0.f, 0.f, 0.f, 0.f};
#pragma unroll
        for (int ks = 0; ks < 8; ++ks) {
            const int kk = ks * 32;
            short8 a[2];
#pragma unroll
            for (int mm = 0; mm < 2; ++mm) {
                if (mm < mm_n) {
                    if (kk < 128) {
                        int xr = 8 * (mc + mm) + (L >> 1);
                        if (xr >= cnt) xr = 0;
                        a[mm] = *(const short8*)(xc + xr * XSTR + kk + q * 8);
                    } else if (!GCH) {
                        a[mm] = *(const short8*)(hin_l + (16 * (mc + mm) + L) * HSTR + (kk - 128) + q * 8);
                    } else {
                        a[mm] = *(const short8*)(hin_g + (size_t)(cb + 16 * (mc + mm) + L) * DIM + (kk - 128) + q * 8);
                    }
                }
            }
#pragma unroll
            for (int g = 0; g < 4; ++g)
#pragma unroll
                for (int mm = 0; mm < 2; ++mm)
                    if (mm < mm_n)
                        acc[mm][g] = __builtin_amdgcn_mfma_f32_16x16x32_bf16(a[mm], b[ks * 4 + g], acc[mm][g], 0, 0, 0);
        }
#pragma unroll
        for (int mm = 0; mm < 2; ++mm)
#pragma unroll
            for (int e = 0; e < 2; ++e) {
                if (mm < mm_n) {
                    const int nl = 8 * (mc + mm) + 2 * q + e;
                    if (nl < cnt) {
                        const int r0 = 2 * e, r1 = 2 * e + 1;
                        float iv = sigm(acc[mm][0][r0] + acc[mm][0][r1] + biasWU[ch]);
                        float ov = sigm(acc[mm][1][r0] + acc[mm][1][r1] + biasWU[128 + ch]);
                        float uv = ftanh(acc[mm][2][r0] + acc[mm][2][r1] + biasWU[256 + ch]);
                        float fl = sigm(acc[mm][3][r0] + biasWU[384 + ch]);
                        float fr = sigm(acc[mm][3][r1] + biasWU[384 + ch]);
                        float cl, cr;
                        if (!GCH) {
                            cl = cin_l[(2 * nl) * CSTR + ch];
                            cr = cin_l[(2 * nl + 1) * CSTR + ch];
                        } else {
                            cl = cin_g[(size_t)(cb + 2 * nl) * DIM + ch];
                            cr = cin_g[(size_t)(cb + 2 * nl + 1) * DIM + ch];
                        }
                        float cv = iv * uv + fl * cl + fr * cr;
                        co[nl * co_str + ch] = cv;
                        ho[nl * ho_str + ch] = f2bf(ov * ftanh(cv));
                    }
                }
            }
    }
}

// ---------- k23 subtree body (device function; bx = index within phase) ----------
template <int C, int NL, bool PROJ>
__device__ void k23_body(const float* __restrict__ x, const short8 (&b)[32],
                         const float* __restrict__ biasWU,
                         unsigned short* __restrict__ hbf, float* __restrict__ cbuf,
                         int d0, int bx,
                         unsigned short* xs, unsigned short* hA, unsigned short* hB,
                         float* cA, float* cB, float* red,
                         const float* __restrict__ Wp, const float* __restrict__ bWp,
                         float* __restrict__ out,
                         int tid, int L, int q, int ch) {
    {
        int xoff = 0;
#pragma unroll
        for (int l = 0; l < NL; ++l) {
            const int rows = C >> l;
            const long base = ((1 << (d0 - l)) - 1) + (long)bx * rows;
            for (int i = tid; i < rows * 32; i += 512) {
                const int row = i >> 5, j = i & 31;
                float4 v = *(const float4*)(x + (size_t)(base + row) * DIM + j * 4);
                ushort4 o;
                o.x = f2bf(v.x); o.y = f2bf(v.y); o.z = f2bf(v.z); o.w = f2bf(v.w);
                *(ushort4*)(xs + (xoff + row) * XSTR + j * 4) = o;
            }
            xoff += rows;
        }
    }
    __syncthreads();

    const long cb = ((1 << (d0 + 1)) - 1) + (long)bx * (2 * C);
    internal_level<true>(xs, nullptr, nullptr, hbf, cbuf, cb,
                         hA, HSTR, cA, CSTR, C, b, biasWU, L, q, ch);
    __syncthreads();

    const unsigned short* hin = hA;
    const float* cin = cA;
    int xoff = C;
#pragma unroll
    for (int l = 1; l < NL; ++l) {
        const int cnt = C >> l;
        if (!PROJ && l == NL - 1) {
            const long ob = ((1 << (d0 - (NL - 1))) - 1) + (long)bx;
            internal_level<false>(xs + xoff * XSTR, hin, cin, nullptr, nullptr, 0,
                                  hbf + (size_t)ob * DIM, DIM,
                                  cbuf + (size_t)ob * DIM, DIM, cnt, b, biasWU, L, q, ch);
        } else {
            unsigned short* ho = (l & 1) ? hB : hA;
            float* co = (l & 1) ? cB : cA;
            internal_level<false>(xs + xoff * XSTR, hin, cin, nullptr, nullptr, 0,
                                  ho, HSTR, co, CSTR, cnt, b, biasWU, L, q, ch);
            __syncthreads();
            hin = ho; cin = co;
        }
        xoff += cnt;
    }

    if (PROJ) {
        const int o = tid & 127, sg = tid >> 7;
        float pacc = 0.f;
#pragma unroll
        for (int jj = 0; jj < 8; ++jj) {
            const int k = sg * 32 + jj * 4;
            float4 wv = *(const float4*)(Wp + o * DIM + k);
            pacc += bf2f(hin[k]) * wv.x + bf2f(hin[k + 1]) * wv.y +
                    bf2f(hin[k + 2]) * wv.z + bf2f(hin[k + 3]) * wv.w;
        }
        red[sg * 128 + o] = pacc;
        __syncthreads();
        if (tid < 128) out[tid] = bWp[tid] + red[tid] + red[128 + tid] + red[256 + tid] + red[384 + tid];
    }
}

// ---------- tail kernel: phases B, C, D, E with software grid barriers ----------
// LDS pool carve (shorts):
//  kd2 phase: xs 0(6528) | hc 6528(8704) | h0 15232(4352) | c0 19584(4352) |
//             hA1 23936(2176) | cA1 @26112 (f32, 8448B)  -> 60672 B total
//  k23 phase: xs 0(8568) | hA 8568(4352) | hB 12920(2176) | cA @15096 (16896B)
//             | cB @23544 (8448B) | red @27768 (2048B)    -> 57584 B total
__global__ __launch_bounds__(512, 2) void tail_kernel(
    const float* __restrict__ x, const unsigned short* __restrict__ Bsw,
    const float* __restrict__ biasWU,
    unsigned short* __restrict__ hbf, float* __restrict__ cbuf,
    const float* __restrict__ Wp, const float* __restrict__ bWp,
    float* __restrict__ out, unsigned* __restrict__ bar) {
    __shared__ __align__(16) unsigned short pool[30336];

    const int tid = threadIdx.x;
    const int w = tid >> 6, lane = tid & 63, L = lane & 15, q = lane >> 4;
    const int ch = w * 16 + L;

    short8 b[32];
#pragma unroll
    for (int t = 0; t < 32; ++t)
        b[t] = *(const short8*)(Bsw + ((size_t)w << 14) + (t << 9) + lane * 8);

    unsigned short* xsB  = pool;
    unsigned short* hcB  = pool + 6528;
    unsigned short* h0B  = pool + 15232;
    unsigned short* c0B  = pool + 19584;
    unsigned short* hA1B = pool + 23936;
    float*          cA1B = (float*)(pool + 26112);

    // ---- Phase B: d14 + d13, 512 tiles (2 per block) ----
    for (int it = 0; it < 2; ++it) {
        const long tt = (long)it * 256 + blockIdx.x;
        kd2_tile(x, b, biasWU, hbf, cbuf,
                 (long)((1 << 14) - 1) + tt * 32, (long)((1 << 13) - 1) + tt * 16,
                 xsB, hcB, h0B, c0B, hA1B, cA1B, tid, L, q, ch);
    }
    gbar(bar + 0, 256);

    // ---- Phase C: d12 + d11, 128 tiles (blocks < 128) ----
    if (blockIdx.x < 128) {
        const long tt = blockIdx.x;
        kd2_tile(x, b, biasWU, hbf, cbuf,
                 (long)((1 << 12) - 1) + tt * 32, (long)((1 << 11) - 1) + tt * 16,
                 xsB, hcB, h0B, c0B, hA1B, cA1B, tid, L, q, ch);
    }
    gbar(bar + 1, 256);

    unsigned short* xsK = pool;
    unsigned short* hAK = pool + 8568;
    unsigned short* hBK = pool + 12920;
    float*          cAK = (float*)(pool + 15096);
    float*          cBK = (float*)(pool + 23544);
    float*          redK = (float*)(pool + 27768);

    // ---- Phase D: d10..d5, 32 subtrees (blocks < 32) ----
    if (blockIdx.x < 32)
        k23_body<32, 6, false>(x, b, biasWU, hbf, cbuf, 10, blockIdx.x,
                               xsK, hAK, hBK, cAK, cBK, redK,
                               nullptr, nullptr, nullptr, tid, L, q, ch);
    gbar(bar + 2, 256);

    // ---- Phase E: d4..d0 + projection (block 0) ----
    if (blockIdx.x == 0)
        k23_body<16, 5, true>(x, b, biasWU, hbf, cbuf, 4, 0,
                              xsK, hAK, hBK, cAK, cBK, redK,
                              Wp, bWp, out, tid, L, q, ch);
}

extern "C" void kernel_launch(void* const* d_in, const int* in_sizes, int n_in,
                              void* d_out, int out_size, void* d_ws, size_t ws_size,
                              hipStream_t stream) {
    const float* x   = (const float*)d_in[0];
    const float* Wi  = (const float*)d_in[2];  const float* bWi = (const float*)d_in[3];
    const float* Ui  = (const float*)d_in[4];  const float* bUi = (const float*)d_in[5];
    const float* Wf  = (const float*)d_in[6];  const float* bWf = (const float*)d_in[7];
    const float* Uf  = (const float*)d_in[8];  const float* bUf = (const float*)d_in[9];
    const float* Wo  = (const float*)d_in[10]; const float* bWo = (const float*)d_in[11];
    const float* Uo  = (const float*)d_in[12]; const float* bUo = (const float*)d_in[13];
    const float* Wu  = (const float*)d_in[14]; const float* bWu = (const float*)d_in[15];
    const float* Uu  = (const float*)d_in[16]; const float* bUu = (const float*)d_in[17];
    const float* Wp  = (const float*)d_in[18]; const float* bWp = (const float*)d_in[19];

    // ws: Bsw (131072 bf16) | biasWU(512 f32) | biasL(512 f32) |
    //     cbuf (65536*128 f32) | hbf (65536*128 bf16) | bar (4 u32)
    unsigned short* Bsw = (unsigned short*)d_ws;
    float* biasWU = (float*)(Bsw + 131072);
    float* biasL  = biasWU + 512;
    float* cbuf   = biasL + 512;
    unsigned short* hbf = (unsigned short*)(cbuf + (size_t)65536 * DIM);
    unsigned* bar = (unsigned*)(hbf + (size_t)65536 * DIM);

    WPtrs p;
    p.W[0] = Wi; p.W[1] = Wo; p.W[2] = Wu; p.W[3] = Wf;
    p.U[0] = Ui; p.U[1] = Uo; p.U[2] = Uu; p.U[3] = Uf;
    p.bW[0] = bWi; p.bW[1] = bWo; p.bW[2] = bWu; p.bW[3] = bWf;
    p.bU[0] = bUi; p.bU[1] = bUo; p.bU[2] = bUu; p.bU[3] = bUf;

    prep_kernel<<<512, 256, 0, stream>>>(p, Bsw, biasWU, biasL, bar);

    // K_A: d16 (leaves) + d15, 2048 tiles, persistent grid 256 x 8 tiles.
    kd2r_kernel<true><<<256, 512, 0, stream>>>(x, Bsw, biasL, biasWU, hbf, cbuf,
                                               (1 << 16) - 1, (1 << 15) - 1, 8);
    // Tail: d14 .. d0 + projection, one persistent kernel with grid barriers.
    tail_kernel<<<256, 512, 0, stream>>>(x, Bsw, biasWU, hbf, cbuf,
                                         Wp, bWp, (float*)d_out, bar);
}

// Round 5
// 244.756 us; speedup vs baseline: 1.2216x; 1.2216x over previous
//
#include <hip/hip_runtime.h>
#include <hip/hip_bf16.h>

// ChildSumTreeLSTM, complete binary tree heap layout (children of n: 2n+1, 2n+2).
// R15: R14's merge regressed (gbar fences + de-pipelined tiles cost more than
// launch boundaries; tail measured 142us at <5% util = serialization). Reverted
// to separate kernels. New: kd3_kernel covers d16+d15+d14 in ONE pass (2048
// tiles of 32 leaves + 16 d15 + 8 d14; 3 barriers/tile). d15 h/c never leave
// LDS (bf16) -> saves ~50 MB of global h/c round-trip and moves half the old
// K_B work into the efficient leaf kernel. d14 out via overlapped store (R13
// trick: store(t-1) after B1(t)). Tail: kd2r(d13+d12, 256 tiles) +
// kd2r(d11+d10, 64) + k23(d9..d5, 32 blocks) + k23(d4..d0+proj, 1 block).
// Register wall (R11): b[32]=128 AGPR + ~128 VGPR = 256/wave cap, 8 waves/CU,
// 1 block/CU. pfx grows 12->16 VGPR here (watch for spill next round).
// Bsw = fragment-stream-ordered [W/2 | U] (f-gate W unhalved), gates [i,o,u,f];
// child row r computes [x_par; h_child]@B^T, epilogue sums row pairs in-lane.

#define DEPTH 17
#define NTREE ((1 << DEPTH) - 1)  // 131071
#define DIM 128
#define XSTR 136  // bf16 LDS row stride (shorts) = 272 B (16B-aligned, 2-way banks = free)
#define HSTR 136
#define CSTR 132  // fp32 LDS row stride (floats)

typedef __attribute__((ext_vector_type(8))) short short8;
typedef __attribute__((ext_vector_type(4))) float float4v;

__device__ __forceinline__ float sigm(float v) {
    return __fdividef(1.0f, 1.0f + __expf(-v));
}
__device__ __forceinline__ float ftanh(float v) {
    float e = __expf(2.0f * v);                  // inf-safe: e=inf -> 1, e=0 -> -1
    return 1.0f - __fdividef(2.0f, e + 1.0f);
}

__device__ __forceinline__ unsigned short f2bf(float f) {
    __bf16 h = (__bf16)f;  // HW RNE cvt
    unsigned short r;
    __builtin_memcpy(&r, &h, 2);
    return r;
}
__device__ __forceinline__ float bf2f(unsigned short s) {
    union { unsigned u; float f; } a; a.u = ((unsigned)s) << 16;
    return a.f;
}

struct WPtrs {
    const float* W[4];  const float* U[4];
    const float* bW[4]; const float* bU[4];
};

// Bsw[w][ks][g][lane][j] (w:8, ks:8, g:4, lane:64, j:8) = fragment-stream order.
__global__ __launch_bounds__(256) void prep_kernel(WPtrs p, unsigned short* __restrict__ Bsw,
                                                   float* __restrict__ biasWU, float* __restrict__ biasL) {
    int idx = blockIdx.x * 256 + threadIdx.x;  // 0 .. 131071
    int j = idx & 7;
    int lane = (idx >> 3) & 63;
    int g = (idx >> 9) & 3;
    int ks = (idx >> 11) & 7;
    int w = idx >> 14;
    int L = lane & 15, q = lane >> 4;
    int c = w * 16 + L;
    int k = ks * 32 + q * 8 + j;
    float v = (k < 128) ? p.W[g][c * 128 + k] * (g == 3 ? 1.0f : 0.5f)
                        : p.U[g][c * 128 + (k - 128)];
    Bsw[idx] = f2bf(v);
    if (idx < 512) {
        int gg = idx >> 7, cc = idx & 127;
        biasWU[idx] = p.bW[gg][cc] + p.bU[gg][cc];
        biasL[idx]  = p.bW[gg][cc];
    }
}

// ---------- K_A: depth-3 leaf kernel (d16 + d15 + d14), 3 barriers/tile ----------
// Tile tt: 32 leaves (65535+32tt), 16 d15 (32767+16tt), 8 d14 (16383+8tt).
// Rows in xs: 0..31 leaf x | 32..47 d15 x | 48..55 d14 x.
// Per tile: publish | B1 | prefetch + store(t-1) + L0 | B2 | L1 | B3 | L2.
__global__ __launch_bounds__(512, 2) void kd3_kernel(
    const float* __restrict__ x, const unsigned short* __restrict__ Bsw,
    const float* __restrict__ biasL, const float* __restrict__ biasWU,
    unsigned short* __restrict__ hbf, float* __restrict__ cbuf, int ntiles) {
    __shared__ __align__(16) unsigned short xs[2][56 * XSTR];  // dbuf
    __shared__ __align__(16) unsigned short h0[32 * XSTR];     // leaf h (bf16)
    __shared__ __align__(16) unsigned short c0[32 * XSTR];     // leaf c (bf16)
    __shared__ __align__(16) unsigned short h1[16 * XSTR];     // d15 h (bf16)
    __shared__ __align__(16) unsigned short c1[16 * XSTR];     // d15 c (bf16)
    __shared__ __align__(16) unsigned short hA2[8 * XSTR];     // d14 h out
    __shared__ __align__(16) float cA2[8 * CSTR];              // d14 c out

    const int tid = threadIdx.x;
    const int w = tid >> 6, lane = tid & 63, L = lane & 15, q = lane >> 4;
    const int ch = w * 16 + L;

    short8 b[32];
#pragma unroll
    for (int t = 0; t < 32; ++t)
        b[t] = *(const short8*)(Bsw + ((size_t)w << 14) + (t << 9) + lane * 8);

    // prefetch: 56 rows * 32 float4 = 1792 granules; 4/thread (k=3 for tid<256)
    float4 pfx[4];
    {
        const long tt = blockIdx.x;
#pragma unroll
        for (int k = 0; k < 4; ++k) {
            const int i = tid + 512 * k;
            if (i < 1792) {
                const int row = i >> 5, j = i & 31;
                const long node = (row < 32) ? (65535l + tt * 32 + row)
                                 : (row < 48) ? (32767l + tt * 16 + (row - 32))
                                              : (16383l + tt * 8 + (row - 48));
                pfx[k] = *(const float4*)(x + (size_t)node * DIM + j * 4);
            }
        }
    }

    for (int it = 0; it < ntiles; ++it) {
        const long tt = (long)it * gridDim.x + blockIdx.x;
        const int pc = it & 1;
        unsigned short* xsp = xs[pc];

        // publish prefetched x (bf16)
#pragma unroll
        for (int k = 0; k < 4; ++k) {
            const int i = tid + 512 * k;
            if (i < 1792) {
                const int row = i >> 5, j = i & 31;
                ushort4 o;
                o.x = f2bf(pfx[k].x); o.y = f2bf(pfx[k].y);
                o.z = f2bf(pfx[k].z); o.w = f2bf(pfx[k].w);
                *(ushort4*)(xsp + row * XSTR + j * 4) = o;
            }
        }
        __syncthreads();  // B1

        // issue next tile's x prefetch (in flight across all 3 levels)
        if (it + 1 < ntiles) {
            const long tn = tt + gridDim.x;
#pragma unroll
            for (int k = 0; k < 4; ++k) {
                const int i = tid + 512 * k;
                if (i < 1792) {
                    const int row = i >> 5, j = i & 31;
                    const long node = (row < 32) ? (65535l + tn * 32 + row)
                                     : (row < 48) ? (32767l + tn * 16 + (row - 32))
                                                  : (16383l + tn * 8 + (row - 48));
                    pfx[k] = *(const float4*)(x + (size_t)node * DIM + j * 4);
                }
            }
        }

        // store tile t-1's 8 d14 rows (overlaps L0 compute; hA2/cA2 rewritten
        // only after B3(t), and these reads finish before this wave's B2)
        if (it > 0) {
            const long pn2 = 16383l + (tt - gridDim.x) * 8;
            for (int i = tid; i < 8 * 16; i += 512) {
                const int row = i >> 4, g = i & 15;
                *(uint4*)(hbf + (size_t)(pn2 + row) * DIM + g * 8) = *(const uint4*)(hA2 + row * XSTR + g * 8);
            }
            for (int i = tid; i < 8 * 32; i += 512) {
                const int row = i >> 5, j = i & 31;
                *(float4*)(cbuf + (size_t)(pn2 + row) * DIM + j * 4) = *(const float4*)(cA2 + row * CSTR + j * 4);
            }
        }

        // ---- L0: 32 leaves (K=128, gates i,o,u, logit = 2*acc + bW) ----
        {
            float4v acc[2][3];
#pragma unroll
            for (int mm = 0; mm < 2; ++mm)
#pragma unroll
                for (int g = 0; g < 3; ++g) acc[mm][g] = (float4v){0.f, 0.f, 0.f, 0.f};
#pragma unroll
            for (int ks = 0; ks < 4; ++ks) {
                short8 a[2];
                a[0] = *(const short8*)(xsp + L * XSTR + ks * 32 + q * 8);
                a[1] = *(const short8*)(xsp + (16 + L) * XSTR + ks * 32 + q * 8);
#pragma unroll
                for (int g = 0; g < 3; ++g)
#pragma unroll
                    for (int mm = 0; mm < 2; ++mm)
                        acc[mm][g] = __builtin_amdgcn_mfma_f32_16x16x32_bf16(a[mm], b[ks * 4 + g], acc[mm][g], 0, 0, 0);
            }
#pragma unroll
            for (int mm = 0; mm < 2; ++mm)
#pragma unroll
                for (int r = 0; r < 4; ++r) {
                    const int nl = 16 * mm + q * 4 + r;
                    float iv = sigm(2.f * acc[mm][0][r] + biasL[ch]);
                    float ov = sigm(2.f * acc[mm][1][r] + biasL[128 + ch]);
                    float uv = ftanh(2.f * acc[mm][2][r] + biasL[256 + ch]);
                    float cv = iv * uv;
                    c0[nl * XSTR + ch] = f2bf(cv);
                    h0[nl * XSTR + ch] = f2bf(ov * ftanh(cv));
                }
        }
        __syncthreads();  // B2

        // ---- L1: 16 d15 nodes (children = 32 leaf rows in LDS) ----
        {
            float4v acc[2][4];
#pragma unroll
            for (int mm = 0; mm < 2; ++mm)
#pragma unroll
                for (int g = 0; g < 4; ++g) acc[mm][g] = (float4v){0.f, 0.f, 0.f, 0.f};
#pragma unroll
            for (int ks = 0; ks < 8; ++ks) {
                const int kk = ks * 32;
                short8 a[2];
#pragma unroll
                for (int mm = 0; mm < 2; ++mm) {
                    if (kk < 128)
                        a[mm] = *(const short8*)(xsp + (32 + 8 * mm + (L >> 1)) * XSTR + kk + q * 8);
                    else
                        a[mm] = *(const short8*)(h0 + (16 * mm + L) * XSTR + (kk - 128) + q * 8);
                }
#pragma unroll
                for (int g = 0; g < 4; ++g)
#pragma unroll
                    for (int mm = 0; mm < 2; ++mm)
                        acc[mm][g] = __builtin_amdgcn_mfma_f32_16x16x32_bf16(a[mm], b[ks * 4 + g], acc[mm][g], 0, 0, 0);
            }
#pragma unroll
            for (int mm = 0; mm < 2; ++mm)
#pragma unroll
                for (int e = 0; e < 2; ++e) {
                    const int nl = 8 * mm + 2 * q + e;
                    const int r0 = 2 * e, r1 = 2 * e + 1;
                    float iv = sigm(acc[mm][0][r0] + acc[mm][0][r1] + biasWU[ch]);
                    float ov = sigm(acc[mm][1][r0] + acc[mm][1][r1] + biasWU[128 + ch]);
                    float uv = ftanh(acc[mm][2][r0] + acc[mm][2][r1] + biasWU[256 + ch]);
                    float fl = sigm(acc[mm][3][r0] + biasWU[384 + ch]);
                    float fr = sigm(acc[mm][3][r1] + biasWU[384 + ch]);
                    float cl = bf2f(c0[(2 * nl) * XSTR + ch]);
                    float cr = bf2f(c0[(2 * nl + 1) * XSTR + ch]);
                    float cv = iv * uv + fl * cl + fr * cr;
                    c1[nl * XSTR + ch] = f2bf(cv);
                    h1[nl * XSTR + ch] = f2bf(ov * ftanh(cv));
                }
        }
        __syncthreads();  // B3

        // ---- L2: 8 d14 nodes (children = 16 d15 rows in LDS); one m-frag ----
        {
            float4v acc[4];
#pragma unroll
            for (int g = 0; g < 4; ++g) acc[g] = (float4v){0.f, 0.f, 0.f, 0.f};
#pragma unroll
            for (int ks = 0; ks < 8; ++ks) {
                const int kk = ks * 32;
                short8 a;
                if (kk < 128)
                    a = *(const short8*)(xsp + (48 + (L >> 1)) * XSTR + kk + q * 8);
                else
                    a = *(const short8*)(h1 + L * XSTR + (kk - 128) + q * 8);
#pragma unroll
                for (int g = 0; g < 4; ++g)
                    acc[g] = __builtin_amdgcn_mfma_f32_16x16x32_bf16(a, b[ks * 4 + g], acc[g], 0, 0, 0);
            }
#pragma unroll
            for (int e = 0; e < 2; ++e) {
                const int nl = 2 * q + e;
                const int r0 = 2 * e, r1 = 2 * e + 1;
                float iv = sigm(acc[0][r0] + acc[0][r1] + biasWU[ch]);
                float ov = sigm(acc[1][r0] + acc[1][r1] + biasWU[128 + ch]);
                float uv = ftanh(acc[2][r0] + acc[2][r1] + biasWU[256 + ch]);
                float fl = sigm(acc[3][r0] + biasWU[384 + ch]);
                float fr = sigm(acc[3][r1] + biasWU[384 + ch]);
                float cl = bf2f(c1[(2 * nl) * XSTR + ch]);
                float cr = bf2f(c1[(2 * nl + 1) * XSTR + ch]);
                float cv = iv * uv + fl * cl + fr * cr;
                cA2[nl * CSTR + ch] = cv;
                hA2[nl * XSTR + ch] = f2bf(ov * ftanh(cv));
            }
        }
    }

    // drain: store the last tile's 8 d14 rows
    __syncthreads();
    {
        const long tl = (long)(ntiles - 1) * gridDim.x + blockIdx.x;
        const long n2 = 16383l + tl * 8;
        for (int i = tid; i < 8 * 16; i += 512) {
            const int row = i >> 4, g = i & 15;
            *(uint4*)(hbf + (size_t)(n2 + row) * DIM + g * 8) = *(const uint4*)(hA2 + row * XSTR + g * 8);
        }
        for (int i = tid; i < 8 * 32; i += 512) {
            const int row = i >> 5, j = i & 31;
            *(float4*)(cbuf + (size_t)(n2 + row) * DIM + j * 4) = *(const float4*)(cA2 + row * CSTR + j * 4);
        }
    }
}

// ---------- persistent depth-2 kernel, 2 barriers/tile (R13 kd2r, non-leaf) ----------
template <bool LEAF0>
__global__ __launch_bounds__(512, 2) void kd2r_kernel(
    const float* __restrict__ x, const unsigned short* __restrict__ Bsw,
    const float* __restrict__ biasL, const float* __restrict__ biasWU,
    unsigned short* __restrict__ hbf, float* __restrict__ cbuf,
    int x0base, int x1base, int ntiles) {
    __shared__ __align__(16) unsigned short xs[2][48 * XSTR];
    __shared__ __align__(16) unsigned short hc[LEAF0 ? 16 : 64 * XSTR];
    __shared__ __align__(16) unsigned short h0[32 * XSTR];
    __shared__ __align__(16) unsigned short c0[32 * XSTR];
    __shared__ __align__(16) unsigned short hA1[16 * XSTR];
    __shared__ __align__(16) float cA1[16 * CSTR];

    const int tid = threadIdx.x;
    const int w = tid >> 6, lane = tid & 63, L = lane & 15, q = lane >> 4;
    const int ch = w * 16 + L;

    short8 b[32];
#pragma unroll
    for (int t = 0; t < 32; ++t)
        b[t] = *(const short8*)(Bsw + ((size_t)w << 14) + (t << 9) + lane * 8);

    float4 pfx[3];
    {
        const long tt = blockIdx.x;
        const long n0 = (long)x0base + tt * 32, n1 = (long)x1base + tt * 16;
#pragma unroll
        for (int k = 0; k < 3; ++k) {
            const int i = tid + 512 * k;
            const int row = i >> 5, j = i & 31;
            const long node = (row < 32) ? (n0 + row) : (n1 + (row - 32));
            pfx[k] = *(const float4*)(x + (size_t)node * DIM + j * 4);
        }
    }

    for (int it = 0; it < ntiles; ++it) {
        const long tt = (long)it * gridDim.x + blockIdx.x;
        const long n0 = (long)x0base + tt * 32;
        const long n1 = (long)x1base + tt * 16;
        const long cb = 2 * n0 + 1;
        const int pc = it & 1;
        unsigned short* xsp = xs[pc];

#pragma unroll
        for (int k = 0; k < 3; ++k) {
            const int i = tid + 512 * k;
            const int row = i >> 5, j = i & 31;
            ushort4 o;
            o.x = f2bf(pfx[k].x); o.y = f2bf(pfx[k].y);
            o.z = f2bf(pfx[k].z); o.w = f2bf(pfx[k].w);
            *(ushort4*)(xsp + row * XSTR + j * 4) = o;
        }
        if (!LEAF0) {
            for (int i = tid; i < 64 * 16; i += 512) {
                const int row = i >> 4, g = i & 15;
                *(uint4*)(hc + row * XSTR + g * 8) =
                    *(const uint4*)(hbf + (size_t)(cb + row) * DIM + g * 8);
            }
        }
        __syncthreads();  // B1

        if (it + 1 < ntiles) {
            const long tn = tt + gridDim.x;
            const long m0 = (long)x0base + tn * 32, m1 = (long)x1base + tn * 16;
#pragma unroll
            for (int k = 0; k < 3; ++k) {
                const int i = tid + 512 * k;
                const int row = i >> 5, j = i & 31;
                const long node = (row < 32) ? (m0 + row) : (m1 + (row - 32));
                pfx[k] = *(const float4*)(x + (size_t)node * DIM + j * 4);
            }
        }

        if (it > 0) {  // store tile t-1's level-1 rows (overlaps L0)
            const long pn1 = n1 - (long)gridDim.x * 16;
            for (int i = tid; i < 16 * 16; i += 512) {
                const int row = i >> 4, g = i & 15;
                *(uint4*)(hbf + (size_t)(pn1 + row) * DIM + g * 8) = *(const uint4*)(hA1 + row * XSTR + g * 8);
            }
            for (int i = tid; i < 16 * 32; i += 512) {
                const int row = i >> 5, j = i & 31;
                *(float4*)(cbuf + (size_t)(pn1 + row) * DIM + j * 4) = *(const float4*)(cA1 + row * CSTR + j * 4);
            }
        }

        // ---- level 0 ----
        if (LEAF0) {
            float4v acc[2][3];
#pragma unroll
            for (int mm = 0; mm < 2; ++mm)
#pragma unroll
                for (int g = 0; g < 3; ++g) acc[mm][g] = (float4v){0.f, 0.f, 0.f, 0.f};
#pragma unroll
            for (int ks = 0; ks < 4; ++ks) {
                short8 a[2];
                a[0] = *(const short8*)(xsp + L * XSTR + ks * 32 + q * 8);
                a[1] = *(const short8*)(xsp + (16 + L) * XSTR + ks * 32 + q * 8);
#pragma unroll
                for (int g = 0; g < 3; ++g)
#pragma unroll
                    for (int mm = 0; mm < 2; ++mm)
                        acc[mm][g] = __builtin_amdgcn_mfma_f32_16x16x32_bf16(a[mm], b[ks * 4 + g], acc[mm][g], 0, 0, 0);
            }
#pragma unroll
            for (int mm = 0; mm < 2; ++mm)
#pragma unroll
                for (int r = 0; r < 4; ++r) {
                    const int nl = 16 * mm + q * 4 + r;
                    float iv = sigm(2.f * acc[mm][0][r] + biasL[ch]);
                    float ov = sigm(2.f * acc[mm][1][r] + biasL[128 + ch]);
                    float uv = ftanh(2.f * acc[mm][2][r] + biasL[256 + ch]);
                    float cv = iv * uv;
                    c0[nl * XSTR + ch] = f2bf(cv);
                    h0[nl * XSTR + ch] = f2bf(ov * ftanh(cv));
                }
        } else {
            for (int mc = 0; mc < 4; mc += 2) {
                float4v acc[2][4];
#pragma unroll
                for (int mm = 0; mm < 2; ++mm)
#pragma unroll
                    for (int g = 0; g < 4; ++g) acc[mm][g] = (float4v){0.f, 0.f, 0.f, 0.f};
#pragma unroll
                for (int ks = 0; ks < 8; ++ks) {
                    const int kk = ks * 32;
                    short8 a[2];
#pragma unroll
                    for (int mm = 0; mm < 2; ++mm) {
                        if (kk < 128)
                            a[mm] = *(const short8*)(xsp + (8 * (mc + mm) + (L >> 1)) * XSTR + kk + q * 8);
                        else
                            a[mm] = *(const short8*)(hc + (16 * (mc + mm) + L) * XSTR + (kk - 128) + q * 8);
                    }
#pragma unroll
                    for (int g = 0; g < 4; ++g)
#pragma unroll
                        for (int mm = 0; mm < 2; ++mm)
                            acc[mm][g] = __builtin_amdgcn_mfma_f32_16x16x32_bf16(a[mm], b[ks * 4 + g], acc[mm][g], 0, 0, 0);
                }
#pragma unroll
                for (int mm = 0; mm < 2; ++mm)
#pragma unroll
                    for (int e = 0; e < 2; ++e) {
                        const int nl = 8 * (mc + mm) + 2 * q + e;
                        const int r0 = 2 * e, r1 = 2 * e + 1;
                        float iv = sigm(acc[mm][0][r0] + acc[mm][0][r1] + biasWU[ch]);
                        float ov = sigm(acc[mm][1][r0] + acc[mm][1][r1] + biasWU[128 + ch]);
                        float uv = ftanh(acc[mm][2][r0] + acc[mm][2][r1] + biasWU[256 + ch]);
                        float fl = sigm(acc[mm][3][r0] + biasWU[384 + ch]);
                        float fr = sigm(acc[mm][3][r1] + biasWU[384 + ch]);
                        float cl = cbuf[(size_t)(cb + 2 * nl) * DIM + ch];
                        float cr = cbuf[(size_t)(cb + 2 * nl + 1) * DIM + ch];
                        float cv = iv * uv + fl * cl + fr * cr;
                        c0[nl * XSTR + ch] = f2bf(cv);
                        h0[nl * XSTR + ch] = f2bf(ov * ftanh(cv));
                    }
            }
        }
        __syncthreads();  // B2

        // ---- level 1 ----
        {
            float4v acc[2][4];
#pragma unroll
            for (int mm = 0; mm < 2; ++mm)
#pragma unroll
                for (int g = 0; g < 4; ++g) acc[mm][g] = (float4v){0.f, 0.f, 0.f, 0.f};
#pragma unroll
            for (int ks = 0; ks < 8; ++ks) {
                const int kk = ks * 32;
                short8 a[2];
#pragma unroll
                for (int mm = 0; mm < 2; ++mm) {
                    if (kk < 128)
                        a[mm] = *(const short8*)(xsp + (32 + 8 * mm + (L >> 1)) * XSTR + kk + q * 8);
                    else
                        a[mm] = *(const short8*)(h0 + (16 * mm + L) * XSTR + (kk - 128) + q * 8);
                }
#pragma unroll
                for (int g = 0; g < 4; ++g)
#pragma unroll
                    for (int mm = 0; mm < 2; ++mm)
                        acc[mm][g] = __builtin_amdgcn_mfma_f32_16x16x32_bf16(a[mm], b[ks * 4 + g], acc[mm][g], 0, 0, 0);
            }
#pragma unroll
            for (int mm = 0; mm < 2; ++mm)
#pragma unroll
                for (int e = 0; e < 2; ++e) {
                    const int nl = 8 * mm + 2 * q + e;
                    const int r0 = 2 * e, r1 = 2 * e + 1;
                    float iv = sigm(acc[mm][0][r0] + acc[mm][0][r1] + biasWU[ch]);
                    float ov = sigm(acc[mm][1][r0] + acc[mm][1][r1] + biasWU[128 + ch]);
                    float uv = ftanh(acc[mm][2][r0] + acc[mm][2][r1] + biasWU[256 + ch]);
                    float fl = sigm(acc[mm][3][r0] + biasWU[384 + ch]);
                    float fr = sigm(acc[mm][3][r1] + biasWU[384 + ch]);
                    float cl = bf2f(c0[(2 * nl) * XSTR + ch]);
                    float cr = bf2f(c0[(2 * nl + 1) * XSTR + ch]);
                    float cv = iv * uv + fl * cl + fr * cr;
                    cA1[nl * CSTR + ch] = cv;
                    hA1[nl * XSTR + ch] = f2bf(ov * ftanh(cv));
                }
        }
    }

    __syncthreads();
    {
        const long tl = (long)(ntiles - 1) * gridDim.x + blockIdx.x;
        const long n1 = (long)x1base + tl * 16;
        for (int i = tid; i < 16 * 16; i += 512) {
            const int row = i >> 4, g = i & 15;
            *(uint4*)(hbf + (size_t)(n1 + row) * DIM + g * 8) = *(const uint4*)(hA1 + row * XSTR + g * 8);
        }
        for (int i = tid; i < 16 * 32; i += 512) {
            const int row = i >> 5, j = i & 31;
            *(float4*)(cbuf + (size_t)(n1 + row) * DIM + j * 4) = *(const float4*)(cA1 + row * CSTR + j * 4);
        }
    }
}

// ---------- k23: fused multi-level subtree (fp32 x staging) ----------
template <bool GCH>
__device__ __forceinline__ void internal_level(
    const unsigned short* xc,
    const unsigned short* hin_l, const float* cin_l,
    const unsigned short* __restrict__ hin_g, const float* __restrict__ cin_g, long cb,
    unsigned short* ho, int ho_str, float* co, int co_str, int cnt,
    const short8 (&b)[32], const float* __restrict__ biasWU,
    int L, int q, int ch) {
    const int rows = 2 * cnt;
    const int mt = (rows + 15) >> 4;
    for (int mc = 0; mc < mt; mc += 2) {
        const int mm_n = (mt - mc >= 2) ? 2 : 1;
        float4v acc[2][4];
#pragma unroll
        for (int mm = 0; mm < 2; ++mm)
#pragma unroll
            for (int g = 0; g < 4; ++g) acc[mm][g] = (float4v){0.f, 0.f, 0.f, 0.f};
#pragma unroll
        for (int ks = 0; ks < 8; ++ks) {
            const int kk = ks * 32;
            short8 a[2];
#pragma unroll
            for (int mm = 0; mm < 2; ++mm) {
                if (mm < mm_n) {
                    if (kk < 128) {
                        int xr = 8 * (mc + mm) + (L >> 1);
                        if (xr >= cnt) xr = 0;
                        a[mm] = *(const short8*)(xc + xr * XSTR + kk + q * 8);
                    } else if (!GCH) {
                        a[mm] = *(const short8*)(hin_l + (16 * (mc + mm) + L) * HSTR + (kk - 128) + q * 8);
                    } else {
                        a[mm] = *(const short8*)(hin_g + (size_t)(cb + 16 * (mc + mm) + L) * DIM + (kk - 128) + q * 8);
                    }
                }
            }
#pragma unroll
            for (int g = 0; g < 4; ++g)
#pragma unroll
                for (int mm = 0; mm < 2; ++mm)
                    if (mm < mm_n)
                        acc[mm][g] = __builtin_amdgcn_mfma_f32_16x16x32_bf16(a[mm], b[ks * 4 + g], acc[mm][g], 0, 0, 0);
        }
#pragma unroll
        for (int mm = 0; mm < 2; ++mm)
#pragma unroll
            for (int e = 0; e < 2; ++e) {
                if (mm < mm_n) {
                    const int nl = 8 * (mc + mm) + 2 * q + e;
                    if (nl < cnt) {
                        const int r0 = 2 * e, r1 = 2 * e + 1;
                        float iv = sigm(acc[mm][0][r0] + acc[mm][0][r1] + biasWU[ch]);
                        float ov = sigm(acc[mm][1][r0] + acc[mm][1][r1] + biasWU[128 + ch]);
                        float uv = ftanh(acc[mm][2][r0] + acc[mm][2][r1] + biasWU[256 + ch]);
                        float fl = sigm(acc[mm][3][r0] + biasWU[384 + ch]);
                        float fr = sigm(acc[mm][3][r1] + biasWU[384 + ch]);
                        float cl, cr;
                        if (!GCH) {
                            cl = cin_l[(2 * nl) * CSTR + ch];
                            cr = cin_l[(2 * nl + 1) * CSTR + ch];
                        } else {
                            cl = cin_g[(size_t)(cb + 2 * nl) * DIM + ch];
                            cr = cin_g[(size_t)(cb + 2 * nl + 1) * DIM + ch];
                        }
                        float cv = iv * uv + fl * cl + fr * cr;
                        co[nl * co_str + ch] = cv;
                        ho[nl * ho_str + ch] = f2bf(ov * ftanh(cv));
                    }
                }
            }
    }
}

// K_D: C=16, NL=5, d0=9 (32 blocks, d9..d5 -> global). K_E: C=16, NL=5, d0=4, PROJ.
template <int C, int NL, bool PROJ>
__global__ __launch_bounds__(512, 2) void k23_kernel(
    const float* __restrict__ x, const unsigned short* __restrict__ Bsw,
    const float* __restrict__ biasWU, unsigned short* __restrict__ hbf,
    float* __restrict__ cbuf, int d0,
    const float* __restrict__ Wp, const float* __restrict__ bWp,
    float* __restrict__ out) {
    constexpr int TOTX = 2 * C - (C >> (NL - 1));
    constexpr int AR = (C < 16) ? 16 : C;
    __shared__ __align__(16) unsigned short xs[TOTX * XSTR];
    __shared__ __align__(16) unsigned short hA[AR * HSTR];
    __shared__ __align__(16) unsigned short hB[16 * HSTR];
    __shared__ __align__(16) float cA[AR * CSTR];
    __shared__ __align__(16) float cB[16 * CSTR];
    __shared__ float red[4][128];

    const int tid = threadIdx.x;
    const int w = tid >> 6, lane = tid & 63, L = lane & 15, q = lane >> 4;
    const int ch = w * 16 + L;

    short8 b[32];
#pragma unroll
    for (int t = 0; t < 32; ++t)
        b[t] = *(const short8*)(Bsw + ((size_t)w << 14) + (t << 9) + lane * 8);

    {
        int xoff = 0;
#pragma unroll
        for (int l = 0; l < NL; ++l) {
            const int rows = C >> l;
            const long base = ((1 << (d0 - l)) - 1) + (long)blockIdx.x * rows;
            for (int i = tid; i < rows * 32; i += 512) {
                const int row = i >> 5, j = i & 31;
                float4 v = *(const float4*)(x + (size_t)(base + row) * DIM + j * 4);
                ushort4 o;
                o.x = f2bf(v.x); o.y = f2bf(v.y); o.z = f2bf(v.z); o.w = f2bf(v.w);
                *(ushort4*)(xs + (xoff + row) * XSTR + j * 4) = o;
            }
            xoff += rows;
        }
    }
    __syncthreads();

    const long cb = ((1 << (d0 + 1)) - 1) + (long)blockIdx.x * (2 * C);
    internal_level<true>(xs, nullptr, nullptr, hbf, cbuf, cb,
                         hA, HSTR, cA, CSTR, C, b, biasWU, L, q, ch);
    __syncthreads();

    const unsigned short* hin = hA;
    const float* cin = cA;
    int xoff = C;
#pragma unroll
    for (int l = 1; l < NL; ++l) {
        const int cnt = C >> l;
        if (!PROJ && l == NL - 1) {
            const long ob = ((1 << (d0 - (NL - 1))) - 1) + (long)blockIdx.x;
            internal_level<false>(xs + xoff * XSTR, hin, cin, nullptr, nullptr, 0,
                                  hbf + (size_t)ob * DIM, DIM,
                                  cbuf + (size_t)ob * DIM, DIM, cnt, b, biasWU, L, q, ch);
        } else {
            unsigned short* ho = (l & 1) ? hB : hA;
            float* co = (l & 1) ? cB : cA;
            internal_level<false>(xs + xoff * XSTR, hin, cin, nullptr, nullptr, 0,
                                  ho, HSTR, co, CSTR, cnt, b, biasWU, L, q, ch);
            __syncthreads();
            hin = ho; cin = co;
        }
        xoff += cnt;
    }

    if (PROJ) {
        const int o = tid & 127, sg = tid >> 7;
        float pacc = 0.f;
#pragma unroll
        for (int jj = 0; jj < 8; ++jj) {
            const int k = sg * 32 + jj * 4;
            float4 wv = *(const float4*)(Wp + o * DIM + k);
            pacc += bf2f(hin[k]) * wv.x + bf2f(hin[k + 1]) * wv.y +
                    bf2f(hin[k + 2]) * wv.z + bf2f(hin[k + 3]) * wv.w;
        }
        red[sg][o] = pacc;
        __syncthreads();
        if (tid < 128) out[tid] = bWp[tid] + red[0][tid] + red[1][tid] + red[2][tid] + red[3][tid];
    }
}

extern "C" void kernel_launch(void* const* d_in, const int* in_sizes, int n_in,
                              void* d_out, int out_size, void* d_ws, size_t ws_size,
                              hipStream_t stream) {
    const float* x   = (const float*)d_in[0];
    const float* Wi  = (const float*)d_in[2];  const float* bWi = (const float*)d_in[3];
    const float* Ui  = (const float*)d_in[4];  const float* bUi = (const float*)d_in[5];
    const float* Wf  = (const float*)d_in[6];  const float* bWf = (const float*)d_in[7];
    const float* Uf  = (const float*)d_in[8];  const float* bUf = (const float*)d_in[9];
    const float* Wo  = (const float*)d_in[10]; const float* bWo = (const float*)d_in[11];
    const float* Uo  = (const float*)d_in[12]; const float* bUo = (const float*)d_in[13];
    const float* Wu  = (const float*)d_in[14]; const float* bWu = (const float*)d_in[15];
    const float* Uu  = (const float*)d_in[16]; const float* bUu = (const float*)d_in[17];
    const float* Wp  = (const float*)d_in[18]; const float* bWp = (const float*)d_in[19];

    // ws: Bsw (131072 bf16) | biasWU(512 f32) | biasL(512 f32) |
    //     cbuf (65536*128 f32) | hbf (65536*128 bf16)
    unsigned short* Bsw = (unsigned short*)d_ws;
    float* biasWU = (float*)(Bsw + 131072);
    float* biasL  = biasWU + 512;
    float* cbuf   = biasL + 512;
    unsigned short* hbf = (unsigned short*)(cbuf + (size_t)65536 * DIM);

    WPtrs p;
    p.W[0] = Wi; p.W[1] = Wo; p.W[2] = Wu; p.W[3] = Wf;
    p.U[0] = Ui; p.U[1] = Uo; p.U[2] = Uu; p.U[3] = Uf;
    p.bW[0] = bWi; p.bW[1] = bWo; p.bW[2] = bWu; p.bW[3] = bWf;
    p.bU[0] = bUi; p.bU[1] = bUo; p.bU[2] = bUu; p.bU[3] = bUf;

    prep_kernel<<<512, 256, 0, stream>>>(p, Bsw, biasWU, biasL);

    // K_A: d16 + d15 + d14, 2048 tiles (32+16+8), persistent grid 256 x 8 tiles.
    kd3_kernel<<<256, 512, 0, stream>>>(x, Bsw, biasL, biasWU, hbf, cbuf, 8);
    // K_B: d13 + d12 (children = d14), 256 tiles, grid 256 x 1.
    kd2r_kernel<false><<<256, 512, 0, stream>>>(x, Bsw, biasL, biasWU, hbf, cbuf,
                                                (1 << 13) - 1, (1 << 12) - 1, 1);
    // K_C: d11 + d10 (children = d12), 64 tiles, grid 64 x 1.
    kd2r_kernel<false><<<64, 512, 0, stream>>>(x, Bsw, biasL, biasWU, hbf, cbuf,
                                               (1 << 11) - 1, (1 << 10) - 1, 1);
    // K_D: d9..d5 (children = d10), 32 blocks.
    k23_kernel<16, 5, false><<<32, 512, 0, stream>>>(x, Bsw, biasWU, hbf, cbuf, 9,
                                                     nullptr, nullptr, nullptr);
    // K_E: d4..d0 + projection (children = d5).
    k23_kernel<16, 5, true><<<1, 512, 0, stream>>>(x, Bsw, biasWU, hbf, cbuf, 4,
                                                   Wp, bWp, (float*)d_out);
}